// Round 1
// baseline (5866.021 us; speedup 1.0000x reference)
//
#include <hip/hip_runtime.h>

#define N_NODES 100000
#define N_EDGES 1600000
// D_IN=128, D_HID=256, D_OUT=128

__device__ __forceinline__ void fma4(float* acc, float a, float4 w) {
    acc[0] = fmaf(a, w.x, acc[0]);
    acc[1] = fmaf(a, w.y, acc[1]);
    acc[2] = fmaf(a, w.z, acc[2]);
    acc[3] = fmaf(a, w.w, acc[3]);
}

// ---------------- scatter-add of 128-dim rows (optionally count degrees) ---------------
// 32 lanes per edge, each lane owns one float4 (16B) of the 512B row.
template<bool COUNT>
__global__ __launch_bounds__(256) void k_scatter(
    const int* __restrict__ src, const int* __restrict__ dst,
    const float* __restrict__ tab, float* __restrict__ agg, float* __restrict__ cnt)
{
    int gid = blockIdx.x * 256 + threadIdx.x;
    int e = gid >> 5;
    if (e >= N_EDGES) return;
    int lane = gid & 31;
    int s = src[e], d = dst[e];
    // clamp: no-op for valid input, prevents segfault if dtype surprises us
    s = s < 0 ? 0 : (s >= N_NODES ? N_NODES - 1 : s);
    d = d < 0 ? 0 : (d >= N_NODES ? N_NODES - 1 : d);
    float4 v = ((const float4*)tab)[(long)s * 32 + lane];
    float* o = agg + (long)d * 128 + lane * 4;
    atomicAdd(o + 0, v.x);
    atomicAdd(o + 1, v.y);
    atomicAdd(o + 2, v.z);
    atomicAdd(o + 3, v.w);
    if (COUNT && lane == 0) atomicAdd(&cnt[d], 1.0f);
}

// cnt -> 1/max(cnt,1), in place
__global__ __launch_bounds__(256) void k_inv(float* __restrict__ cnt)
{
    int n = blockIdx.x * 256 + threadIdx.x;
    if (n < N_NODES) {
        float c = cnt[n];
        cnt[n] = 1.0f / fmaxf(c, 1.0f);
    }
}

// ---------------- layer-1 fused dual GEMM ----------------
// h[n,0:256] = (agg1[n]*inv[n]) @ Wl1 + x[n] @ Wr1 + bl1 + pert[n]
// block: 256 thr, tile 64 rows x 256 cols, K=128 in chunks of 16.
// thread: tc=tid&31 -> cols {tc*4..tc*4+3} and {128+tc*4..}, tr=tid>>5 -> rows tr*8..tr*8+7
__global__ __launch_bounds__(256) void k_gemm1(
    const float* __restrict__ agg1, const float* __restrict__ inv,
    const float* __restrict__ x,
    const float* __restrict__ Wl, const float* __restrict__ Wr,
    const float* __restrict__ bl, const float* __restrict__ pert,
    float* __restrict__ h)
{
    __shared__ float wlS[16 * 256];
    __shared__ float wrS[16 * 256];
    __shared__ float aS[64 * 16];
    __shared__ float xS[64 * 16];
    __shared__ float bS[256];
    const int tid = threadIdx.x;
    const int brow = blockIdx.x * 64;
    const int tc = tid & 31;
    const int tr = tid >> 5;
    float acc[8][8] = {};
    bS[tid] = bl[tid];

    const int srow = tid >> 2, sc4 = tid & 3;   // staging: 64 rows x 4 float4
    const int grow = brow + srow;
    const bool rowok = grow < N_NODES;
    float ivs = rowok ? inv[grow] : 0.0f;

    for (int kc = 0; kc < 128; kc += 16) {
        __syncthreads();
        {
            const float4* wl4 = (const float4*)Wl + kc * 64;
            const float4* wr4 = (const float4*)Wr + kc * 64;
            float4* wlS4 = (float4*)wlS;
            float4* wrS4 = (float4*)wrS;
            #pragma unroll
            for (int i = 0; i < 4; ++i) {
                wlS4[i * 256 + tid] = wl4[i * 256 + tid];
                wrS4[i * 256 + tid] = wr4[i * 256 + tid];
            }
            float4 av = {0, 0, 0, 0}, xv = {0, 0, 0, 0};
            if (rowok) {
                av = ((const float4*)agg1)[(long)grow * 32 + (kc >> 2) + sc4];
                xv = ((const float4*)x)[(long)grow * 32 + (kc >> 2) + sc4];
                av.x *= ivs; av.y *= ivs; av.z *= ivs; av.w *= ivs;
            }
            ((float4*)aS)[tid] = av;
            ((float4*)xS)[tid] = xv;
        }
        __syncthreads();
        #pragma unroll 4
        for (int kk = 0; kk < 16; ++kk) {
            float4 wla = *(const float4*)(wlS + kk * 256 + tc * 4);
            float4 wlb = *(const float4*)(wlS + kk * 256 + 128 + tc * 4);
            float4 wra = *(const float4*)(wrS + kk * 256 + tc * 4);
            float4 wrb = *(const float4*)(wrS + kk * 256 + 128 + tc * 4);
            #pragma unroll
            for (int r = 0; r < 8; ++r) {
                float a = aS[(tr * 8 + r) * 16 + kk];
                float b = xS[(tr * 8 + r) * 16 + kk];
                fma4(acc[r],     a, wla);
                fma4(acc[r],     b, wra);
                fma4(acc[r] + 4, a, wlb);
                fma4(acc[r] + 4, b, wrb);
            }
        }
    }
    #pragma unroll
    for (int r = 0; r < 8; ++r) {
        int row = brow + tr * 8 + r;
        if (row >= N_NODES) continue;
        const float4* p4 = (const float4*)pert + (long)row * 64;
        float4* h4 = (float4*)h + (long)row * 64;
        float4 pa = p4[tc], pb = p4[32 + tc];
        float4 oa, ob;
        oa.x = acc[r][0] + bS[tc * 4 + 0] + pa.x;
        oa.y = acc[r][1] + bS[tc * 4 + 1] + pa.y;
        oa.z = acc[r][2] + bS[tc * 4 + 2] + pa.z;
        oa.w = acc[r][3] + bS[tc * 4 + 3] + pa.w;
        ob.x = acc[r][4] + bS[128 + tc * 4 + 0] + pb.x;
        ob.y = acc[r][5] + bS[128 + tc * 4 + 1] + pb.y;
        ob.z = acc[r][6] + bS[128 + tc * 4 + 2] + pb.z;
        ob.w = acc[r][7] + bS[128 + tc * 4 + 3] + pb.w;
        h4[tc] = oa;
        h4[32 + tc] = ob;
    }
}

// ---------------- layer-2 GEMM (K=256 -> 128 cols) ----------------
// MODE 0: out = hin @ W                      (t2)
// MODE 1: out = hin @ W + agg*inv + bias + pert   (final output)
// block: 256 thr, tile 128 rows x 128 cols, K chunks of 32.
// thread: tc=tid&15 -> cols {tc*4..} and {64+tc*4..}, tr=tid>>4 -> rows tr*8..tr*8+7
template<int MODE>
__global__ __launch_bounds__(256) void k_gemm2(
    const float* __restrict__ hin,
    const float* __restrict__ W,
    const float* __restrict__ agg,
    const float* __restrict__ inv,
    const float* __restrict__ bias,
    const float* __restrict__ pert,
    float* __restrict__ out)
{
    __shared__ float wS[32 * 128];
    __shared__ float hS[128 * 33];   // +1 pad: tr-groups land on distinct banks
    __shared__ float bS[128];
    const int tid = threadIdx.x;
    const int brow = blockIdx.x * 128;
    const int tc = tid & 15;
    const int tr = tid >> 4;
    float acc[8][8] = {};
    if (MODE == 1 && tid < 128) bS[tid] = bias[tid];

    for (int kc = 0; kc < 256; kc += 32) {
        __syncthreads();
        {
            const float4* w4 = (const float4*)W + kc * 32;
            float4* wS4 = (float4*)wS;
            #pragma unroll
            for (int i = 0; i < 4; ++i) wS4[i * 256 + tid] = w4[i * 256 + tid];
            #pragma unroll
            for (int i = 0; i < 4; ++i) {
                int idx = i * 256 + tid;          // 0..1023
                int r = idx >> 3, c4 = idx & 7;   // 128 rows x 8 float4
                int row = brow + r;
                float4 v = {0, 0, 0, 0};
                if (row < N_NODES)
                    v = ((const float4*)hin)[(long)row * 64 + (kc >> 2) + c4];
                float* dp = hS + r * 33 + c4 * 4;
                dp[0] = v.x; dp[1] = v.y; dp[2] = v.z; dp[3] = v.w;
            }
        }
        __syncthreads();
        #pragma unroll 4
        for (int kk = 0; kk < 32; ++kk) {
            float4 wa = *(const float4*)(wS + kk * 128 + tc * 4);
            float4 wb = *(const float4*)(wS + kk * 128 + 64 + tc * 4);
            #pragma unroll
            for (int r = 0; r < 8; ++r) {
                float a = hS[(tr * 8 + r) * 33 + kk];
                fma4(acc[r],     a, wa);
                fma4(acc[r] + 4, a, wb);
            }
        }
    }
    #pragma unroll
    for (int r = 0; r < 8; ++r) {
        int row = brow + tr * 8 + r;
        if (row >= N_NODES) continue;
        float4 oa = {acc[r][0], acc[r][1], acc[r][2], acc[r][3]};
        float4 ob = {acc[r][4], acc[r][5], acc[r][6], acc[r][7]};
        if (MODE == 1) {
            float iv = inv[row];
            const float4* g4 = (const float4*)agg + (long)row * 32;
            const float4* p4 = (const float4*)pert + (long)row * 32;
            float4 ga = g4[tc], gb = g4[16 + tc];
            float4 pa = p4[tc], pb = p4[16 + tc];
            oa.x += ga.x * iv + bS[tc * 4 + 0] + pa.x;
            oa.y += ga.y * iv + bS[tc * 4 + 1] + pa.y;
            oa.z += ga.z * iv + bS[tc * 4 + 2] + pa.z;
            oa.w += ga.w * iv + bS[tc * 4 + 3] + pa.w;
            ob.x += gb.x * iv + bS[64 + tc * 4 + 0] + pb.x;
            ob.y += gb.y * iv + bS[64 + tc * 4 + 1] + pb.y;
            ob.z += gb.z * iv + bS[64 + tc * 4 + 2] + pb.z;
            ob.w += gb.w * iv + bS[64 + tc * 4 + 3] + pb.w;
        }
        ((float4*)out)[(long)row * 32 + tc] = oa;
        ((float4*)out)[(long)row * 32 + 16 + tc] = ob;
    }
}

extern "C" void kernel_launch(void* const* d_in, const int* in_sizes, int n_in,
                              void* d_out, int out_size, void* d_ws, size_t ws_size,
                              hipStream_t stream)
{
    const float* x   = (const float*)d_in[0];
    const int*   ei  = (const int*)d_in[1];
    const float* p1  = (const float*)d_in[2];
    const float* p2  = (const float*)d_in[3];
    const float* Wl1 = (const float*)d_in[4];
    const float* bl1 = (const float*)d_in[5];
    const float* Wr1 = (const float*)d_in[6];
    const float* Wl2 = (const float*)d_in[7];
    const float* bl2 = (const float*)d_in[8];
    const float* Wr2 = (const float*)d_in[9];
    const int* src = ei;
    const int* dst = ei + N_EDGES;

    float* ws   = (float*)d_ws;
    float* agg1 = ws;                               // N*128  (reused as t2)
    float* h    = agg1 + (size_t)N_NODES * 128;     // N*256
    float* agg2 = h    + (size_t)N_NODES * 256;     // N*128
    float* cnt  = agg2 + (size_t)N_NODES * 128;     // N      (becomes inv in place)
    float* t2   = agg1;
    float* out  = (float*)d_out;

    hipMemsetAsync(agg1, 0, (size_t)N_NODES * 128 * sizeof(float), stream);
    hipMemsetAsync(agg2, 0, (size_t)N_NODES * 128 * sizeof(float), stream);
    hipMemsetAsync(cnt,  0, (size_t)N_NODES * sizeof(float), stream);

    const int sblocks = (N_EDGES * 32) / 256;       // 200000
    k_scatter<true><<<sblocks, 256, 0, stream>>>(src, dst, x, agg1, cnt);
    k_inv<<<(N_NODES + 255) / 256, 256, 0, stream>>>(cnt);
    k_gemm1<<<(N_NODES + 63) / 64, 256, 0, stream>>>(agg1, cnt, x, Wl1, Wr1, bl1, p1, h);
    k_gemm2<0><<<(N_NODES + 127) / 128, 256, 0, stream>>>(h, Wl2, nullptr, nullptr, nullptr, nullptr, t2);
    k_scatter<false><<<sblocks, 256, 0, stream>>>(src, dst, t2, agg2, nullptr);
    k_gemm2<1><<<(N_NODES + 127) / 128, 256, 0, stream>>>(h, Wr2, agg2, cnt, bl2, p2, out);
}

// Round 2
// 930.936 us; speedup vs baseline: 6.3012x; 6.3012x over previous
//
#include <hip/hip_runtime.h>

#define N_NODES 100000
#define N_EDGES 1600000
// D_IN=128, D_HID=256, D_OUT=128

__device__ __forceinline__ void fma4(float* acc, float a, float4 w) {
    acc[0] = fmaf(a, w.x, acc[0]);
    acc[1] = fmaf(a, w.y, acc[1]);
    acc[2] = fmaf(a, w.z, acc[2]);
    acc[3] = fmaf(a, w.w, acc[3]);
}

__device__ __forceinline__ int clampN(int v) {
    return v < 0 ? 0 : (v >= N_NODES ? N_NODES - 1 : v);
}

// ---------------- CSR build ----------------
__global__ __launch_bounds__(256) void k_deg(
    const int* __restrict__ dst, int* __restrict__ deg)
{
    int e = blockIdx.x * 256 + threadIdx.x;
    if (e >= N_EDGES) return;
    atomicAdd(&deg[clampN(dst[e])], 1);
}

// exclusive scan of deg[0..N) -> row_ptr[0..N], single block of 1024
__global__ __launch_bounds__(1024) void k_scan(
    const int* __restrict__ deg, int* __restrict__ row_ptr)
{
    __shared__ int ps[1024];
    const int t = threadIdx.x;
    const int chunk = (N_NODES + 1023) / 1024;   // 98
    int lo = t * chunk;
    int hi = lo + chunk; if (hi > N_NODES) hi = N_NODES;
    int sum = 0;
    for (int i = lo; i < hi; ++i) sum += deg[i];
    ps[t] = sum;
    __syncthreads();
    for (int off = 1; off < 1024; off <<= 1) {
        int v = ps[t];
        int add = (t >= off) ? ps[t - off] : 0;
        __syncthreads();
        ps[t] = v + add;
        __syncthreads();
    }
    int run = (t > 0) ? ps[t - 1] : 0;
    for (int i = lo; i < hi; ++i) { row_ptr[i] = run; run += deg[i]; }
    if (t == 1023) row_ptr[N_NODES] = ps[1023];
}

__global__ __launch_bounds__(256) void k_fill(
    const int* __restrict__ src, const int* __restrict__ dst,
    const int* __restrict__ row_ptr, int* __restrict__ cursor,
    int* __restrict__ edge_src)
{
    int e = blockIdx.x * 256 + threadIdx.x;
    if (e >= N_EDGES) return;
    int s = clampN(src[e]);
    int d = clampN(dst[e]);
    int pos = atomicAdd(&cursor[d], 1);
    edge_src[row_ptr[d] + pos] = s;
}

// ---------------- CSR mean-gather: one 64-lane wave per node ----------------
// outm[n] = mean over incoming edges of tab[src], 128-dim rows.
__global__ __launch_bounds__(256) void k_gather(
    const int* __restrict__ row_ptr, const int* __restrict__ edge_src,
    const float* __restrict__ tab, float* __restrict__ outm)
{
    int wid = (blockIdx.x * 256 + threadIdx.x) >> 6;
    int lane = threadIdx.x & 63;
    if (wid >= N_NODES) return;
    int start = row_ptr[wid], end = row_ptr[wid + 1];
    const float2* t2 = (const float2*)tab;
    float ax = 0.0f, ay = 0.0f;
    int e = start;
    for (; e + 3 < end; e += 4) {
        int s0 = edge_src[e], s1 = edge_src[e + 1];
        int s2 = edge_src[e + 2], s3 = edge_src[e + 3];
        float2 v0 = t2[(long)s0 * 64 + lane];
        float2 v1 = t2[(long)s1 * 64 + lane];
        float2 v2 = t2[(long)s2 * 64 + lane];
        float2 v3 = t2[(long)s3 * 64 + lane];
        ax += v0.x + v1.x + v2.x + v3.x;
        ay += v0.y + v1.y + v2.y + v3.y;
    }
    for (; e < end; ++e) {
        int s = edge_src[e];
        float2 v = t2[(long)s * 64 + lane];
        ax += v.x; ay += v.y;
    }
    float invd = 1.0f / fmaxf((float)(end - start), 1.0f);
    float2 o; o.x = ax * invd; o.y = ay * invd;
    ((float2*)outm)[(long)wid * 64 + lane] = o;
}

// ---------------- layer-1 fused dual GEMM ----------------
// h[n,0:256] = agg1[n] @ Wl1 + x[n] @ Wr1 + bl1 + pert[n]   (agg1 already mean)
__global__ __launch_bounds__(256) void k_gemm1(
    const float* __restrict__ agg1, const float* __restrict__ x,
    const float* __restrict__ Wl, const float* __restrict__ Wr,
    const float* __restrict__ bl, const float* __restrict__ pert,
    float* __restrict__ h)
{
    __shared__ float wlS[16 * 256];
    __shared__ float wrS[16 * 256];
    __shared__ float aS[64 * 16];
    __shared__ float xS[64 * 16];
    __shared__ float bS[256];
    const int tid = threadIdx.x;
    const int brow = blockIdx.x * 64;
    const int tc = tid & 31;
    const int tr = tid >> 5;
    float acc[8][8] = {};
    bS[tid] = bl[tid];

    const int srow = tid >> 2, sc4 = tid & 3;   // staging: 64 rows x 4 float4
    const int grow = brow + srow;
    const bool rowok = grow < N_NODES;

    for (int kc = 0; kc < 128; kc += 16) {
        __syncthreads();
        {
            const float4* wl4 = (const float4*)Wl + kc * 64;
            const float4* wr4 = (const float4*)Wr + kc * 64;
            float4* wlS4 = (float4*)wlS;
            float4* wrS4 = (float4*)wrS;
            #pragma unroll
            for (int i = 0; i < 4; ++i) {
                wlS4[i * 256 + tid] = wl4[i * 256 + tid];
                wrS4[i * 256 + tid] = wr4[i * 256 + tid];
            }
            float4 av = {0, 0, 0, 0}, xv = {0, 0, 0, 0};
            if (rowok) {
                av = ((const float4*)agg1)[(long)grow * 32 + (kc >> 2) + sc4];
                xv = ((const float4*)x)[(long)grow * 32 + (kc >> 2) + sc4];
            }
            ((float4*)aS)[tid] = av;
            ((float4*)xS)[tid] = xv;
        }
        __syncthreads();
        #pragma unroll 4
        for (int kk = 0; kk < 16; ++kk) {
            float4 wla = *(const float4*)(wlS + kk * 256 + tc * 4);
            float4 wlb = *(const float4*)(wlS + kk * 256 + 128 + tc * 4);
            float4 wra = *(const float4*)(wrS + kk * 256 + tc * 4);
            float4 wrb = *(const float4*)(wrS + kk * 256 + 128 + tc * 4);
            #pragma unroll
            for (int r = 0; r < 8; ++r) {
                float a = aS[(tr * 8 + r) * 16 + kk];
                float b = xS[(tr * 8 + r) * 16 + kk];
                fma4(acc[r],     a, wla);
                fma4(acc[r],     b, wra);
                fma4(acc[r] + 4, a, wlb);
                fma4(acc[r] + 4, b, wrb);
            }
        }
    }
    #pragma unroll
    for (int r = 0; r < 8; ++r) {
        int row = brow + tr * 8 + r;
        if (row >= N_NODES) continue;
        const float4* p4 = (const float4*)pert + (long)row * 64;
        float4* h4 = (float4*)h + (long)row * 64;
        float4 pa = p4[tc], pb = p4[32 + tc];
        float4 oa, ob;
        oa.x = acc[r][0] + bS[tc * 4 + 0] + pa.x;
        oa.y = acc[r][1] + bS[tc * 4 + 1] + pa.y;
        oa.z = acc[r][2] + bS[tc * 4 + 2] + pa.z;
        oa.w = acc[r][3] + bS[tc * 4 + 3] + pa.w;
        ob.x = acc[r][4] + bS[128 + tc * 4 + 0] + pb.x;
        ob.y = acc[r][5] + bS[128 + tc * 4 + 1] + pb.y;
        ob.z = acc[r][6] + bS[128 + tc * 4 + 2] + pb.z;
        ob.w = acc[r][7] + bS[128 + tc * 4 + 3] + pb.w;
        h4[tc] = oa;
        h4[32 + tc] = ob;
    }
}

// ---------------- layer-2 GEMM (K=256 -> 128 cols) ----------------
// MODE 0: out = hin @ W                        (t2)
// MODE 1: out = hin @ W + agg + bias + pert    (agg already mean; out may alias agg)
template<int MODE>
__global__ __launch_bounds__(256) void k_gemm2(
    const float* __restrict__ hin,
    const float* __restrict__ W,
    const float* __restrict__ agg,
    const float* __restrict__ bias,
    const float* __restrict__ pert,
    float* __restrict__ out)
{
    __shared__ float wS[32 * 128];
    __shared__ float hS[128 * 33];
    __shared__ float bS[128];
    const int tid = threadIdx.x;
    const int brow = blockIdx.x * 128;
    const int tc = tid & 15;
    const int tr = tid >> 4;
    float acc[8][8] = {};
    if (MODE == 1 && tid < 128) bS[tid] = bias[tid];

    for (int kc = 0; kc < 256; kc += 32) {
        __syncthreads();
        {
            const float4* w4 = (const float4*)W + kc * 32;
            float4* wS4 = (float4*)wS;
            #pragma unroll
            for (int i = 0; i < 4; ++i) wS4[i * 256 + tid] = w4[i * 256 + tid];
            #pragma unroll
            for (int i = 0; i < 4; ++i) {
                int idx = i * 256 + tid;          // 0..1023
                int r = idx >> 3, c4 = idx & 7;   // 128 rows x 8 float4
                int row = brow + r;
                float4 v = {0, 0, 0, 0};
                if (row < N_NODES)
                    v = ((const float4*)hin)[(long)row * 64 + (kc >> 2) + c4];
                float* dp = hS + r * 33 + c4 * 4;
                dp[0] = v.x; dp[1] = v.y; dp[2] = v.z; dp[3] = v.w;
            }
        }
        __syncthreads();
        #pragma unroll 4
        for (int kk = 0; kk < 32; ++kk) {
            float4 wa = *(const float4*)(wS + kk * 128 + tc * 4);
            float4 wb = *(const float4*)(wS + kk * 128 + 64 + tc * 4);
            #pragma unroll
            for (int r = 0; r < 8; ++r) {
                float a = hS[(tr * 8 + r) * 33 + kk];
                fma4(acc[r],     a, wa);
                fma4(acc[r] + 4, a, wb);
            }
        }
    }
    #pragma unroll
    for (int r = 0; r < 8; ++r) {
        int row = brow + tr * 8 + r;
        if (row >= N_NODES) continue;
        float4 oa = {acc[r][0], acc[r][1], acc[r][2], acc[r][3]};
        float4 ob = {acc[r][4], acc[r][5], acc[r][6], acc[r][7]};
        if (MODE == 1) {
            const float4* g4 = (const float4*)agg + (long)row * 32;
            const float4* p4 = (const float4*)pert + (long)row * 32;
            float4 ga = g4[tc], gb = g4[16 + tc];
            float4 pa = p4[tc], pb = p4[16 + tc];
            oa.x += ga.x + bS[tc * 4 + 0] + pa.x;
            oa.y += ga.y + bS[tc * 4 + 1] + pa.y;
            oa.z += ga.z + bS[tc * 4 + 2] + pa.z;
            oa.w += ga.w + bS[tc * 4 + 3] + pa.w;
            ob.x += gb.x + bS[64 + tc * 4 + 0] + pb.x;
            ob.y += gb.y + bS[64 + tc * 4 + 1] + pb.y;
            ob.z += gb.z + bS[64 + tc * 4 + 2] + pb.z;
            ob.w += gb.w + bS[64 + tc * 4 + 3] + pb.w;
        }
        ((float4*)out)[(long)row * 32 + tc] = oa;
        ((float4*)out)[(long)row * 32 + 16 + tc] = ob;
    }
}

extern "C" void kernel_launch(void* const* d_in, const int* in_sizes, int n_in,
                              void* d_out, int out_size, void* d_ws, size_t ws_size,
                              hipStream_t stream)
{
    const float* x   = (const float*)d_in[0];
    const int*   ei  = (const int*)d_in[1];
    const float* p1  = (const float*)d_in[2];
    const float* p2  = (const float*)d_in[3];
    const float* Wl1 = (const float*)d_in[4];
    const float* bl1 = (const float*)d_in[5];
    const float* Wr1 = (const float*)d_in[6];
    const float* Wl2 = (const float*)d_in[7];
    const float* bl2 = (const float*)d_in[8];
    const float* Wr2 = (const float*)d_in[9];
    const int* src = ei;
    const int* dst = ei + N_EDGES;

    // workspace layout
    float* agg1 = (float*)d_ws;                     // N*128 floats (reused as t2)
    float* h    = agg1 + (size_t)N_NODES * 128;     // N*256 floats
    int* ip     = (int*)(h + (size_t)N_NODES * 256);
    int* deg      = ip;                             // N
    int* cursor   = deg + N_NODES;                  // N
    int* row_ptr  = cursor + N_NODES;               // N+1
    int* edge_src = row_ptr + N_NODES + 1;          // E
    float* t2  = agg1;
    float* out = (float*)d_out;                     // also used as agg2 (in-place)

    hipMemsetAsync(deg,    0, (size_t)N_NODES * sizeof(int), stream);
    hipMemsetAsync(cursor, 0, (size_t)N_NODES * sizeof(int), stream);

    const int eblocks = (N_EDGES + 255) / 256;
    const int gblocks = (N_NODES * 64 + 255) / 256;   // one wave per node
    k_deg<<<eblocks, 256, 0, stream>>>(dst, deg);
    k_scan<<<1, 1024, 0, stream>>>(deg, row_ptr);
    k_fill<<<eblocks, 256, 0, stream>>>(src, dst, row_ptr, cursor, edge_src);

    k_gather<<<gblocks, 256, 0, stream>>>(row_ptr, edge_src, x, agg1);
    k_gemm1<<<(N_NODES + 63) / 64, 256, 0, stream>>>(agg1, x, Wl1, Wr1, bl1, p1, h);
    k_gemm2<0><<<(N_NODES + 127) / 128, 256, 0, stream>>>(h, Wl2, nullptr, nullptr, nullptr, t2);
    k_gather<<<gblocks, 256, 0, stream>>>(row_ptr, edge_src, t2, out);
    k_gemm2<1><<<(N_NODES + 127) / 128, 256, 0, stream>>>(h, Wr2, out, bl2, p2, out);
}

// Round 3
// 679.854 us; speedup vs baseline: 8.6284x; 1.3693x over previous
//
#include <hip/hip_runtime.h>

#define N_NODES 100000
#define N_EDGES 1600000
// D_IN=128, D_HID=256, D_OUT=128

typedef float v4f __attribute__((ext_vector_type(4)));
typedef __bf16 v8bf __attribute__((ext_vector_type(8)));
typedef __bf16 v4bf __attribute__((ext_vector_type(4)));
typedef unsigned int v4u __attribute__((ext_vector_type(4)));

union FragU { v4u u; v8bf b; };
union PkU { unsigned int u; __bf16 h[2]; };

__device__ __forceinline__ int clampN(int v) {
    return v < 0 ? 0 : (v >= N_NODES ? N_NODES - 1 : v);
}
__device__ __forceinline__ float bfhi(unsigned int u) { return __uint_as_float(u & 0xffff0000u); }
__device__ __forceinline__ float bflo(unsigned int u) { return __uint_as_float(u << 16); }

// ---------------- CSR build ----------------
__global__ __launch_bounds__(256) void k_deg(
    const int* __restrict__ dst, int* __restrict__ deg)
{
    int e = blockIdx.x * 256 + threadIdx.x;
    if (e >= N_EDGES) return;
    atomicAdd(&deg[clampN(dst[e])], 1);
}

__global__ __launch_bounds__(1024) void k_scan(
    const int* __restrict__ deg, int* __restrict__ row_ptr)
{
    __shared__ int ps[1024];
    const int t = threadIdx.x;
    const int chunk = (N_NODES + 1023) / 1024;
    int lo = t * chunk;
    int hi = lo + chunk; if (hi > N_NODES) hi = N_NODES;
    int sum = 0;
    for (int i = lo; i < hi; ++i) sum += deg[i];
    ps[t] = sum;
    __syncthreads();
    for (int off = 1; off < 1024; off <<= 1) {
        int v = ps[t];
        int add = (t >= off) ? ps[t - off] : 0;
        __syncthreads();
        ps[t] = v + add;
        __syncthreads();
    }
    int run = (t > 0) ? ps[t - 1] : 0;
    for (int i = lo; i < hi; ++i) { row_ptr[i] = run; run += deg[i]; }
    if (t == 1023) row_ptr[N_NODES] = ps[1023];
}

__global__ __launch_bounds__(256) void k_fill(
    const int* __restrict__ src, const int* __restrict__ dst,
    const int* __restrict__ row_ptr, int* __restrict__ cursor,
    int* __restrict__ edge_src)
{
    int e = blockIdx.x * 256 + threadIdx.x;
    if (e >= N_EDGES) return;
    int s = clampN(src[e]);
    int d = clampN(dst[e]);
    int pos = atomicAdd(&cursor[d], 1);
    edge_src[row_ptr[d] + pos] = s;
}

// ---------------- dtype prep ----------------
__global__ __launch_bounds__(256) void k_cvt_x(
    const float* __restrict__ x, __bf16* __restrict__ xb, int n4)
{
    int t = blockIdx.x * 256 + threadIdx.x;
    if (t >= n4) return;
    float4 v = ((const float4*)x)[t];
    v4bf o = { (__bf16)v.x, (__bf16)v.y, (__bf16)v.z, (__bf16)v.w };
    *(v4bf*)(xb + (size_t)t * 4) = o;
}

// pack W [K][N] fp32 -> MFMA b-frag order: frag fi=(kc*NT+nt), lane l, elem j:
//   Wp[(fi*64+l)*8+j] = bf16(W[kc*32+(l>>4)*8+j][nt*16+(l&15)])
__global__ __launch_bounds__(256) void k_pack_w(
    const float* __restrict__ W, __bf16* __restrict__ Wp, int K, int N)
{
    int t = blockIdx.x * 256 + threadIdx.x;
    int NT = N >> 4;
    int total = (K >> 5) * NT * 64;
    if (t >= total) return;
    int l = t & 63;
    int fi = t >> 6;
    int kc = fi / NT, nt = fi % NT;
    int k0 = kc * 32 + (l >> 4) * 8;
    int col = nt * 16 + (l & 15);
    v8bf o;
    #pragma unroll
    for (int j = 0; j < 8; ++j) o[j] = (__bf16)W[(size_t)(k0 + j) * N + col];
    *(v8bf*)(Wp + (size_t)t * 8) = o;
}

// ---------------- CSR mean-gather (bf16 table), one wave per node ----------------
__global__ __launch_bounds__(256) void k_gather_bf(
    const int* __restrict__ rp, const int* __restrict__ es,
    const __bf16* __restrict__ tab, __bf16* __restrict__ outm)
{
    int wid = (blockIdx.x * 256 + threadIdx.x) >> 6;
    int lane = threadIdx.x & 63;
    if (wid >= N_NODES) return;
    int start = rp[wid], end = rp[wid + 1];
    const unsigned int* t = (const unsigned int*)tab;   // 2 bf16 per uint, 64/row
    float ax = 0.f, ay = 0.f;
    int e = start;
    for (; e + 3 < end; e += 4) {
        int s0 = es[e], s1 = es[e + 1], s2 = es[e + 2], s3 = es[e + 3];
        unsigned int u0 = t[(size_t)s0 * 64 + lane];
        unsigned int u1 = t[(size_t)s1 * 64 + lane];
        unsigned int u2 = t[(size_t)s2 * 64 + lane];
        unsigned int u3 = t[(size_t)s3 * 64 + lane];
        ax += bflo(u0) + bflo(u1) + bflo(u2) + bflo(u3);
        ay += bfhi(u0) + bfhi(u1) + bfhi(u2) + bfhi(u3);
    }
    for (; e < end; ++e) {
        unsigned int u = t[(size_t)es[e] * 64 + lane];
        ax += bflo(u); ay += bfhi(u);
    }
    float invd = 1.f / fmaxf((float)(end - start), 1.f);
    PkU p; p.h[0] = (__bf16)(ax * invd); p.h[1] = (__bf16)(ay * invd);
    ((unsigned int*)outm)[(size_t)wid * 64 + lane] = p.u;
}

// gather mean of bf16 table, ADD into fp32 out (out pre-filled by k_fused)
__global__ __launch_bounds__(256) void k_gather_add(
    const int* __restrict__ rp, const int* __restrict__ es,
    const __bf16* __restrict__ tab, float* __restrict__ outp)
{
    int wid = (blockIdx.x * 256 + threadIdx.x) >> 6;
    int lane = threadIdx.x & 63;
    if (wid >= N_NODES) return;
    int start = rp[wid], end = rp[wid + 1];
    const unsigned int* t = (const unsigned int*)tab;
    float ax = 0.f, ay = 0.f;
    int e = start;
    for (; e + 3 < end; e += 4) {
        int s0 = es[e], s1 = es[e + 1], s2 = es[e + 2], s3 = es[e + 3];
        unsigned int u0 = t[(size_t)s0 * 64 + lane];
        unsigned int u1 = t[(size_t)s1 * 64 + lane];
        unsigned int u2 = t[(size_t)s2 * 64 + lane];
        unsigned int u3 = t[(size_t)s3 * 64 + lane];
        ax += bflo(u0) + bflo(u1) + bflo(u2) + bflo(u3);
        ay += bfhi(u0) + bfhi(u1) + bfhi(u2) + bfhi(u3);
    }
    for (; e < end; ++e) {
        unsigned int u = t[(size_t)es[e] * 64 + lane];
        ax += bflo(u); ay += bfhi(u);
    }
    float invd = 1.f / fmaxf((float)(end - start), 1.f);
    float2* o = (float2*)outp + (size_t)wid * 64 + lane;
    float2 v = *o;
    v.x += ax * invd;
    v.y += ay * invd;
    *o = v;
}

// ---------------- fused MFMA: G1 (h) -> LDS -> G2 (t2 + out_partial) ----------------
// block: 256 thr = 4 waves (2x2), tile 64 rows. G1: wave 32x128 of h[64,256].
// G2: wave 32x64 of t2/out[64,128]. h lives only in XOR-swizzled LDS.
__global__ __launch_bounds__(256) void k_fused(
    const __bf16* __restrict__ aggb, const __bf16* __restrict__ xb,
    const __bf16* __restrict__ Wl1p, const __bf16* __restrict__ Wr1p,
    const float* __restrict__ bl1, const float* __restrict__ p1,
    const __bf16* __restrict__ Wl2p, const __bf16* __restrict__ Wr2p,
    const float* __restrict__ bl2, const float* __restrict__ p2,
    __bf16* __restrict__ t2b, float* __restrict__ outp)
{
    __shared__ __bf16 hS[64 * 256];
    char* hB = (char*)hS;
    const int tid = threadIdx.x;
    const int l = tid & 63, w = tid >> 6;
    const int wr = w >> 1, wc = w & 1;
    const int brow = blockIdx.x * 64;
    const int lrow = l & 15, kg = l >> 4;
    const v4f zf = {0.f, 0.f, 0.f, 0.f};

    // ---- G1 ----
    v4f acc[2][8];
    #pragma unroll
    for (int i = 0; i < 2; ++i)
        #pragma unroll
        for (int j = 0; j < 8; ++j) acc[i][j] = zf;

    float blv1[8];
    #pragma unroll
    for (int nt = 0; nt < 8; ++nt) blv1[nt] = bl1[wc * 128 + nt * 16 + lrow];

    int arow[2];
    #pragma unroll
    for (int rb = 0; rb < 2; ++rb) {
        int r = brow + wr * 32 + rb * 16 + lrow;
        arow[rb] = r < N_NODES ? r : N_NODES - 1;
    }

    #pragma unroll
    for (int kc = 0; kc < 4; ++kc) {
        FragU ag[2], xv[2];
        #pragma unroll
        for (int rb = 0; rb < 2; ++rb) {
            size_t off = (size_t)arow[rb] * 128 + kc * 32 + kg * 8;
            ag[rb].u = *(const v4u*)(aggb + off);
            xv[rb].u = *(const v4u*)(xb + off);
        }
        #pragma unroll
        for (int nt = 0; nt < 8; ++nt) {
            int ntg = wc * 8 + nt;
            FragU bwl, bwr;
            bwl.u = *(const v4u*)(Wl1p + ((size_t)(kc * 16 + ntg) * 64 + l) * 8);
            bwr.u = *(const v4u*)(Wr1p + ((size_t)(kc * 16 + ntg) * 64 + l) * 8);
            #pragma unroll
            for (int rb = 0; rb < 2; ++rb) {
                acc[rb][nt] = __builtin_amdgcn_mfma_f32_16x16x32_bf16(ag[rb].b, bwl.b, acc[rb][nt], 0, 0, 0);
                acc[rb][nt] = __builtin_amdgcn_mfma_f32_16x16x32_bf16(xv[rb].b, bwr.b, acc[rb][nt], 0, 0, 0);
            }
        }
    }

    // ---- repack h (+bias+pert) into swizzled LDS ----
    #pragma unroll
    for (int rb = 0; rb < 2; ++rb)
        #pragma unroll
        for (int nt = 0; nt < 8; ++nt)
            #pragma unroll
            for (int r = 0; r < 4; ++r) {
                int row = wr * 32 + rb * 16 + kg * 4 + r;     // D row: (lane>>4)*4+reg
                int grow = brow + row;
                int col = wc * 128 + nt * 16 + lrow;          // D col: lane&15
                float hv = acc[rb][nt][r] + blv1[nt];
                if (grow < N_NODES) hv += p1[(size_t)grow * 256 + col];
                int byte = (row * 512 + col * 2) ^ ((row & 7) << 4);
                *(__bf16*)(hB + byte) = (__bf16)hv;
            }
    __syncthreads();

    // ---- G2 ----
    v4f acct[2][4], acco[2][4];
    #pragma unroll
    for (int i = 0; i < 2; ++i)
        #pragma unroll
        for (int j = 0; j < 4; ++j) { acct[i][j] = zf; acco[i][j] = zf; }

    float blv2[4];
    #pragma unroll
    for (int nt = 0; nt < 4; ++nt) blv2[nt] = bl2[wc * 64 + nt * 16 + lrow];

    #pragma unroll
    for (int kc = 0; kc < 8; ++kc) {
        FragU a[2];
        #pragma unroll
        for (int rb = 0; rb < 2; ++rb) {
            int row = wr * 32 + rb * 16 + lrow;
            int byte = (row * 512 + kc * 64 + kg * 16) ^ ((row & 7) << 4);
            a[rb].u = *(const v4u*)(hB + byte);
        }
        #pragma unroll
        for (int nt = 0; nt < 4; ++nt) {
            int ntg = wc * 4 + nt;
            FragU bwl, bwr;
            bwl.u = *(const v4u*)(Wl2p + ((size_t)(kc * 8 + ntg) * 64 + l) * 8);
            bwr.u = *(const v4u*)(Wr2p + ((size_t)(kc * 8 + ntg) * 64 + l) * 8);
            #pragma unroll
            for (int rb = 0; rb < 2; ++rb) {
                acct[rb][nt] = __builtin_amdgcn_mfma_f32_16x16x32_bf16(a[rb].b, bwl.b, acct[rb][nt], 0, 0, 0);
                acco[rb][nt] = __builtin_amdgcn_mfma_f32_16x16x32_bf16(a[rb].b, bwr.b, acco[rb][nt], 0, 0, 0);
            }
        }
    }

    #pragma unroll
    for (int rb = 0; rb < 2; ++rb)
        #pragma unroll
        for (int nt = 0; nt < 4; ++nt)
            #pragma unroll
            for (int r = 0; r < 4; ++r) {
                int row = wr * 32 + rb * 16 + kg * 4 + r;
                int grow = brow + row;
                if (grow >= N_NODES) continue;
                int col = wc * 64 + nt * 16 + lrow;
                t2b[(size_t)grow * 128 + col] = (__bf16)acct[rb][nt][r];
                outp[(size_t)grow * 128 + col] =
                    acco[rb][nt][r] + blv2[nt] + p2[(size_t)grow * 128 + col];
            }
}

extern "C" void kernel_launch(void* const* d_in, const int* in_sizes, int n_in,
                              void* d_out, int out_size, void* d_ws, size_t ws_size,
                              hipStream_t stream)
{
    const float* x   = (const float*)d_in[0];
    const int*   ei  = (const int*)d_in[1];
    const float* p1  = (const float*)d_in[2];
    const float* p2  = (const float*)d_in[3];
    const float* Wl1 = (const float*)d_in[4];
    const float* bl1 = (const float*)d_in[5];
    const float* Wr1 = (const float*)d_in[6];
    const float* Wl2 = (const float*)d_in[7];
    const float* bl2 = (const float*)d_in[8];
    const float* Wr2 = (const float*)d_in[9];
    const int* src = ei;
    const int* dst = ei + N_EDGES;

    char* wp = (char*)d_ws;
    __bf16* xb   = (__bf16*)wp; wp += (size_t)N_NODES * 128 * 2;
    __bf16* aggb = (__bf16*)wp; wp += (size_t)N_NODES * 128 * 2;
    __bf16* t2b  = (__bf16*)wp; wp += (size_t)N_NODES * 128 * 2;
    __bf16* Wl1p = (__bf16*)wp; wp += 128 * 256 * 2;
    __bf16* Wr1p = (__bf16*)wp; wp += 128 * 256 * 2;
    __bf16* Wl2p = (__bf16*)wp; wp += 256 * 128 * 2;
    __bf16* Wr2p = (__bf16*)wp; wp += 256 * 128 * 2;
    int* deg     = (int*)wp; wp += (size_t)N_NODES * 4;
    int* cursor  = (int*)wp; wp += (size_t)N_NODES * 4;
    int* rowp    = (int*)wp; wp += (size_t)(N_NODES + 1) * 4 + 12;
    int* es      = (int*)wp;

    hipMemsetAsync(deg,    0, (size_t)N_NODES * 4, stream);
    hipMemsetAsync(cursor, 0, (size_t)N_NODES * 4, stream);

    const int eblocks = (N_EDGES + 255) / 256;
    const int gblocks = (N_NODES * 64 + 255) / 256;
    const int n4 = N_NODES * 128 / 4;

    k_cvt_x<<<(n4 + 255) / 256, 256, 0, stream>>>(x, xb, n4);
    k_pack_w<<<16, 256, 0, stream>>>(Wl1, Wl1p, 128, 256);
    k_pack_w<<<16, 256, 0, stream>>>(Wr1, Wr1p, 128, 256);
    k_pack_w<<<16, 256, 0, stream>>>(Wl2, Wl2p, 256, 128);
    k_pack_w<<<16, 256, 0, stream>>>(Wr2, Wr2p, 256, 128);
    k_deg<<<eblocks, 256, 0, stream>>>(dst, deg);
    k_scan<<<1, 1024, 0, stream>>>(deg, rowp);
    k_fill<<<eblocks, 256, 0, stream>>>(src, dst, rowp, cursor, es);

    k_gather_bf<<<gblocks, 256, 0, stream>>>(rowp, es, xb, aggb);
    k_fused<<<(N_NODES + 63) / 64, 256, 0, stream>>>(
        aggb, xb, Wl1p, Wr1p, bl1, p1, Wl2p, Wr2p, bl2, p2, t2b, (float*)d_out);
    k_gather_add<<<gblocks, 256, 0, stream>>>(rowp, es, t2b, (float*)d_out);
}